// Round 8
// baseline (291.738 us; speedup 1.0000x reference)
//
#include <hip/hip_runtime.h>

#define TB 512
#define TF 1280
#define TH 2560
#define TK 8
#define TE 9

typedef unsigned short ushortT;
typedef unsigned long long u64;
typedef __attribute__((ext_vector_type(8))) short short8;
typedef __attribute__((ext_vector_type(4))) float floatx4;

__device__ __forceinline__ unsigned short f2bf(float f) {
  union { float f; unsigned u; } v; v.f = f;
  unsigned r = v.u + 0x7fffu + ((v.u >> 16) & 1u);   // RNE
  return (unsigned short)(r >> 16);
}

__device__ __forceinline__ unsigned pk2(float a, float b) {
  union { float f; unsigned u; } ua, ub; ua.f = a; ub.f = b;
  unsigned ra = ua.u + 0x7fffu + ((ua.u >> 16) & 1u);
  unsigned rb = ub.u + 0x7fffu + ((ub.u >> 16) & 1u);
  return __builtin_amdgcn_perm(rb, ra, 0x07060302);  // {ra[31:16], rb[31:16]}
}

__device__ __forceinline__ void gl_lds16(const void* g, void* l) {
  __builtin_amdgcn_global_load_lds(
      (const __attribute__((address_space(1))) unsigned*)g,
      (__attribute__((address_space(3))) unsigned*)l, 16, 0, 0);
}

// ---- prepass: x -> bf16 k-quad [k/4][m][4], W2 -> bf16 transposed [e][n][h]
__global__ __launch_bounds__(256) void prepass(
    const float* __restrict__ x, const float* __restrict__ W2,
    u64* __restrict__ xq, ushortT* __restrict__ W2t) {
  const int i = blockIdx.x * 256 + threadIdx.x;
  if (i < 320 * 512) {
    const int kq = i >> 9, m = i & 511;
    floatx4 v = *(const floatx4*)(x + (long)m * TF + kq * 4);
    xq[i] = (u64)pk2(v.x, v.y) | ((u64)pk2(v.z, v.w) << 32);
  } else {
    const int o = i - 320 * 512;
    if (o < TE * TK * TH) {
      const int hcol = o % TH;
      const int rest = o / TH;
      const int n = rest & 7;
      const int e = rest >> 3;
      W2t[(long)(e * TK + n) * TH + hcol] = f2bf(W2[((long)e * TH + hcol) * TK + n]);
    }
  }
}

// ---- pack_w1: W1 fp32 [e][k][n] -> bf16 k-quad [e][k/4][n][4]  (u64 rows)
__global__ __launch_bounds__(256) void pack_w1(const float* __restrict__ W1,
                                               u64* __restrict__ W1p) {
  const int bid = blockIdx.x;                 // 9 e x 80 ktiles x 10 ntiles
  const int nt = bid % 10;
  const int kt = (bid / 10) % 80;
  const int e  = bid / 800;
  const int t = threadIdx.x;
  const int tk = t >> 6, tc = t & 63;
  const int k0 = kt * 16 + tk * 4;
  const int n0 = nt * 256 + tc * 4;
  const float* src = W1 + ((long)e * TF + k0) * TH + n0;
  floatx4 v0 = *(const floatx4*)(src);
  floatx4 v1 = *(const floatx4*)(src + TH);
  floatx4 v2 = *(const floatx4*)(src + 2 * TH);
  floatx4 v3 = *(const floatx4*)(src + 3 * TH);
  u64 q[4];
#pragma unroll
  for (int i = 0; i < 4; ++i)
    q[i] = (u64)pk2(v0[i], v1[i]) | ((u64)pk2(v2[i], v3[i]) << 32);
  u64* dst = W1p + ((long)(e * 320 + (k0 >> 2)) * TH + n0);
  *(ulonglong2*)(dst)     = make_ulonglong2(q[0], q[1]);
  *(ulonglong2*)(dst + 2) = make_ulonglong2(q[2], q[3]);
}

// ---- gemm1_fused: logacc += relu(x @ W1 + b1) @ W2   (no h materialized)
// BM=128 BN=256 BK=32; 256 thr = 4 waves (2x2), wave = 64m x 128n (4x8 frags).
// R5-proven staging: both operands bf16 k-quad via global_load_lds (6 ops/wave,
// per-lane source = base + lane*16B), single-buffered LDS, 2 barriers/iter.
// 32 MFMA/wave/iter amortize the drain. Requests: B 59MBx4 + A 1.25MBx90 = 348 MB.
__global__ __launch_bounds__(256) void gemm1_fused(
    const u64* __restrict__ xq, const u64* __restrict__ W1p,
    const float* __restrict__ b1, const ushortT* __restrict__ W2t,
    float* __restrict__ logacc) {
  __shared__ __align__(16) char smem[67584];
  u64* Aq = (u64*)smem;                    // [8][130] u64 =  8320 B
  u64* Bq = (u64*)(smem + 8320);           // [8][258] u64 = 16512 B (24832 in-loop)
  ushortT* Ht = (ushortT*)smem;            // [128][264] = 67584 B (epilogue)

  const int t = threadIdx.x;
  const int lane = t & 63, w = t >> 6;
  const int bid = blockIdx.x;
  const int mt = bid & 3;                  // m-siblings adjacent (L3 slab share)
  const int ctile = bid >> 2;              // 0..89
  const int e = ctile / 10;
  const int nbase = (ctile % 10) * 256;
  const int m0 = mt * 128;
  const int wm = w & 1, wn = w >> 1;
  const int lm = lane & 15, lq = lane >> 4;

  const u64* agB = xq + m0 + lane * 2;                              // + kqrow*512
  const u64* bgB = W1p + ((long)e * 320) * TH + nbase + lane * 2;   // + kqrow*TH

  floatx4 acc[4][8];
#pragma unroll
  for (int i = 0; i < 4; ++i)
#pragma unroll
    for (int j = 0; j < 8; ++j) acc[i][j] = (floatx4){0.f, 0.f, 0.f, 0.f};

  for (int kt = 0; kt < 40; ++kt) {
    const int r0 = kt * 8;
    // A: rows w, w+4 (128 u64 = 1 KB each)
    gl_lds16(agB + (long)(r0 + w) * 512, &Aq[w * 130]);
    gl_lds16(agB + (long)(r0 + w + 4) * 512, &Aq[(w + 4) * 130]);
    // B: rows w, w+4 x halves 0,1 (128 u64 each)
    gl_lds16(bgB + (long)(r0 + w) * TH, &Bq[w * 258]);
    gl_lds16(bgB + (long)(r0 + w) * TH + 128, &Bq[w * 258 + 128]);
    gl_lds16(bgB + (long)(r0 + w + 4) * TH, &Bq[(w + 4) * 258]);
    gl_lds16(bgB + (long)(r0 + w + 4) * TH + 128, &Bq[(w + 4) * 258 + 128]);
    __syncthreads();   // drains vmcnt -> tiles visible

    short8 af[4], bf[8];
#pragma unroll
    for (int mg = 0; mg < 4; ++mg) {
      const int m = wm * 64 + mg * 16 + lm;
      ((u64*)&af[mg])[0] = Aq[(2 * lq) * 130 + m];
      ((u64*)&af[mg])[1] = Aq[(2 * lq + 1) * 130 + m];
    }
#pragma unroll
    for (int ng = 0; ng < 8; ++ng) {
      const int n = wn * 128 + ng * 16 + lm;
      ((u64*)&bf[ng])[0] = Bq[(2 * lq) * 258 + n];
      ((u64*)&bf[ng])[1] = Bq[(2 * lq + 1) * 258 + n];
    }
#pragma unroll
    for (int mg = 0; mg < 4; ++mg)
#pragma unroll
      for (int ng = 0; ng < 8; ++ng)
        acc[mg][ng] = __builtin_amdgcn_mfma_f32_16x16x32_bf16(af[mg], bf[ng], acc[mg][ng], 0, 0, 0);
    __syncthreads();   // readers done before next overwrite
  }

  // ---- fused epilogue: bias+relu -> bf16 Ht -> gemm2 partial -> atomicAdd
  float b1v[8];
#pragma unroll
  for (int ng = 0; ng < 8; ++ng)
    b1v[ng] = b1[e * TH + nbase + wn * 128 + ng * 16 + lm];

  // (trailing loop barrier covers Aq/Bq -> Ht overwrite)
#pragma unroll
  for (int mg = 0; mg < 4; ++mg) {
    const int rbase = wm * 64 + mg * 16 + lq * 4;
#pragma unroll
    for (int ng = 0; ng < 8; ++ng) {
      const int col = wn * 128 + ng * 16 + lm;
      floatx4 cv = acc[mg][ng];
#pragma unroll
      for (int r = 0; r < 4; ++r) {
        float v = cv[r] + b1v[ng];
        v = v > 0.f ? v : 0.f;
        Ht[(rbase + r) * 264 + col] = f2bf(v);
      }
    }
  }
  __syncthreads();

  // gemm2 partial: D[j][hrow] = sum_col W2t[e][j][col] * Ht[hrow][col]
#pragma unroll
  for (int g = 0; g < 2; ++g) {
    const int rgb = w * 32 + g * 16;       // 16-row group per wave (128 total)
    floatx4 d = (floatx4){0.f, 0.f, 0.f, 0.f};
#pragma unroll
    for (int kc = 0; kc < 8; ++kc) {
      short8 a;
      if (lm < 8)
        a = *(const short8*)(W2t + ((long)(e * TK + lm)) * TH + nbase + kc * 32 + lq * 8);
      else
        a = (short8){0, 0, 0, 0, 0, 0, 0, 0};
      short8 bfrag = *(const short8*)&Ht[(rgb + lm) * 264 + kc * 32 + lq * 8];
      d = __builtin_amdgcn_mfma_f32_16x16x32_bf16(a, bfrag, d, 0, 0, 0);
    }
    if (lq < 2) {
#pragma unroll
      for (int r = 0; r < 4; ++r)
        atomicAdd(&logacc[((long)e * TB + m0 + rgb + lm) * TK + lq * 4 + r], d[r]);
    }
  }
}

// ---- softmax + leaf products + logits output -------------------------------
__global__ __launch_bounds__(256) void softmax_leaf(
    const float* __restrict__ logacc, const float* __restrict__ b2,
    float* __restrict__ out, float* __restrict__ logits_out) {
  const int b = blockIdx.x * 256 + threadIdx.x;
  if (b >= TB) return;
  float p0[8];
  out[(long)b * 73] = 1.0f;
#pragma unroll
  for (int e = 0; e < TE; ++e) {
    float v[8], mx = -1e30f;
#pragma unroll
    for (int j = 0; j < 8; ++j) {
      v[j] = logacc[((long)e * TB + b) * TK + j] + b2[e * TK + j];
      logits_out[((long)e * TB + b) * TK + j] = v[j];
      mx = fmaxf(mx, v[j]);
    }
    float sm = 0.f;
#pragma unroll
    for (int j = 0; j < 8; ++j) { v[j] = __expf(v[j] - mx); sm += v[j]; }
    const float inv = 1.0f / sm;
    if (e == 0) {
#pragma unroll
      for (int j = 0; j < 8; ++j) {
        p0[j] = v[j] * inv;
        out[(long)b * 73 + 1 + j] = p0[j];
      }
    } else {
      const float pp = p0[e - 1];
#pragma unroll
      for (int j = 0; j < 8; ++j)
        out[(long)b * 73 + 9 + (e - 1) * 8 + j] = pp * v[j] * inv;
    }
  }
}

extern "C" void kernel_launch(void* const* d_in, const int* in_sizes, int n_in,
                              void* d_out, int out_size, void* d_ws, size_t ws_size,
                              hipStream_t stream) {
  const float* x  = (const float*)d_in[0];
  const float* W1 = (const float*)d_in[1];
  const float* b1 = (const float*)d_in[2];
  const float* W2 = (const float*)d_in[3];
  const float* b2 = (const float*)d_in[4];
  float* out = (float*)d_out;

  // ws layout
  float*   logacc = (float*)d_ws;                        //   147,456 B
  u64*     xq     = (u64*)((char*)d_ws + 147456);        // 1,310,720 B
  ushortT* W2t    = (ushortT*)((char*)d_ws + 1458176);   //   368,640 B
  u64*     W1p    = (u64*)((char*)d_ws + 1826816);       // 58,982,400 B
  float* logits_out = out + TB * 73;

  hipMemsetAsync(logacc, 0, (size_t)TE * TB * TK * sizeof(float), stream);
  prepass<<<1360, 256, 0, stream>>>(x, W2, xq, W2t);
  pack_w1<<<7200, 256, 0, stream>>>(W1, W1p);
  gemm1_fused<<<360, 256, 0, stream>>>(xq, W1p, b1, W2t, logacc);
  softmax_leaf<<<2, 256, 0, stream>>>(logacc, b2, out, logits_out);
}